// Round 4
// baseline (664.224 us; speedup 1.0000x reference)
//
#include <hip/hip_runtime.h>

#define PPB   128      // points per block (GEMM M-tile)
#define NZ    8
#define INC   64
#define OUTC  128
#define NB    4
#define HH    256
#define WWD   256
#define HWD   (HH * WWD)
#define DUMP  ((size_t)NB * HWD * OUTC)   // dump slot for padding points (past bev)

// ---------------- binning: histogram ----------------
__global__ void hist_kernel(const int* __restrict__ z_idx, int* __restrict__ counts, int n) {
    __shared__ int lc[NZ];
    int t = threadIdx.x;
    if (t < NZ) lc[t] = 0;
    __syncthreads();
    int i = blockIdx.x * blockDim.x + t;
    if (i < n) {
        int z = z_idx[i]; z = z < 0 ? 0 : (z > NZ - 1 ? NZ - 1 : z);
        atomicAdd(&lc[z], 1);
    }
    __syncthreads();
    if (t < NZ && lc[t] > 0) atomicAdd(&counts[t], lc[t]);
}

// ---------------- binning: padded prefix ----------------
__global__ void prefix_kernel(const int* __restrict__ counts, int* __restrict__ pstart,
                              int* __restrict__ cursors) {
    if (threadIdx.x == 0 && blockIdx.x == 0) {
        int off = 0;
        for (int z = 0; z < NZ; ++z) {
            pstart[z] = off;
            off += ((counts[z] + PPB - 1) / PPB) * PPB;   // pad each bin to PPB multiple
            cursors[z] = 0;
        }
        pstart[NZ] = off;   // padded total
    }
}

// ---------------- binning: scatter point ids + precomputed output offsets ----------------
__global__ void scatter_kernel(const int* __restrict__ z_idx, const int* __restrict__ batch_idx,
                               const int* __restrict__ d0_idx, const int* __restrict__ d1_idx,
                               const int* __restrict__ pstart, int* __restrict__ cursors,
                               int* __restrict__ bins, int* __restrict__ obase, int n) {
    __shared__ int lc[NZ];
    __shared__ int lbase[NZ];
    int t = threadIdx.x;
    if (t < NZ) lc[t] = 0;
    __syncthreads();
    int i = blockIdx.x * blockDim.x + t;
    int z = 0, rank = 0;
    bool valid = (i < n);
    if (valid) {
        z = z_idx[i]; z = z < 0 ? 0 : (z > NZ - 1 ? NZ - 1 : z);
        rank = atomicAdd(&lc[z], 1);
    }
    __syncthreads();
    if (t < NZ) lbase[t] = (lc[t] > 0) ? atomicAdd(&cursors[t], lc[t]) : 0;
    __syncthreads();
    if (valid) {
        int slot = pstart[z] + lbase[z] + rank;
        bins[slot]  = i;
        obase[slot] = (batch_idx[i] * HWD + d0_idx[i] * WWD + d1_idx[i]) * OUTC;
    }
}

// ---------------- main: LDS-tiled fp32 GEMM per z-bin + coalesced atomic scatter ----------------
// Block = 128 points x 128 channels, single z (padded bins guarantee).
// Thread (tp,tc): 8 points (tp*8..+8) x 8 channels {tc*4..+4, 64+tc*4..+4}.
// The 4+4 channel split keeps Wl row reads at worst 2-way bank aliased (free).
__global__ __launch_bounds__(256) void spmm_kernel(
        const float* __restrict__ features, const float* __restrict__ kw,
        const float* __restrict__ bias,
        const int* __restrict__ pstart, const int* __restrict__ bins,
        const int* __restrict__ obase_arr, float* __restrict__ bev) {
    __shared__ __align__(16) float A[INC][PPB];     // 32 KiB, [k][p]
    __shared__ __align__(16) float Wl[INC][OUTC];   // 32 KiB, [k][c]

    int start = blockIdx.x * PPB;
    int total = pstart[NZ];
    if (start >= total) return;
    int z = 0;
#pragma unroll
    for (int zz = 1; zz < NZ; ++zz)
        if (start >= pstart[zz]) z = zz;

    int tid = threadIdx.x;

    // stage W[z]: straight 32KB copy (kw is already [k][c] row-major)
    {
        const float4* src = (const float4*)(kw + (size_t)z * INC * OUTC);
        float4* dst = (float4*)&Wl[0][0];
#pragma unroll
        for (int i = 0; i < 8; ++i) dst[tid + 256 * i] = src[tid + 256 * i];
    }
    // stage A: gather 128 feature rows, write transposed [k][p]
    {
        int r = tid >> 1;                  // point slot 0..127
        int half = tid & 1;                // k halves 0-31 / 32-63
        int raw = bins[start + r];
        int nid = raw < 0 ? 0 : raw;       // padding -> row 0 (result routed to dump)
        const float4* fp = (const float4*)(features + (size_t)nid * INC) + half * 8;
#pragma unroll
        for (int q = 0; q < 8; ++q) {
            float4 f = fp[q];
            int k = half * 32 + q * 4;
            A[k + 0][r] = f.x; A[k + 1][r] = f.y; A[k + 2][r] = f.z; A[k + 3][r] = f.w;
        }
    }
    __syncthreads();

    int tc = tid & 15;
    int tp = tid >> 4;          // 0..15
    int p0 = tp * 8;
    int cl = tc * 4;
    int chh = 64 + tc * 4;

    float acc[8][8];
#pragma unroll
    for (int i = 0; i < 8; ++i)
#pragma unroll
        for (int j = 0; j < 8; ++j) acc[i][j] = 0.f;

#pragma unroll 4
    for (int k = 0; k < INC; ++k) {
        float4 b0 = *(const float4*)&Wl[k][cl];
        float4 b1 = *(const float4*)&Wl[k][chh];
        float4 a0 = *(const float4*)&A[k][p0];
        float4 a1 = *(const float4*)&A[k][p0 + 4];
        float ar[8] = {a0.x, a0.y, a0.z, a0.w, a1.x, a1.y, a1.z, a1.w};
        float br[8] = {b0.x, b0.y, b0.z, b0.w, b1.x, b1.y, b1.z, b1.w};
#pragma unroll
        for (int i = 0; i < 8; ++i)
#pragma unroll
            for (int j = 0; j < 8; ++j)
                acc[i][j] += ar[i] * br[j];
    }

    // bias + coalesced atomic scatter (obase precomputed; padding -> DUMP)
    float4 blo = *(const float4*)&bias[cl];
    float4 bhi = *(const float4*)&bias[chh];
    float bb[8] = {blo.x, blo.y, blo.z, blo.w, bhi.x, bhi.y, bhi.z, bhi.w};
#pragma unroll
    for (int i = 0; i < 8; ++i) {
        int ob = obase_arr[start + p0 + i];
        size_t o = ob < 0 ? DUMP : (size_t)ob;
#pragma unroll
        for (int j = 0; j < 4; ++j)
            unsafeAtomicAdd(&bev[o + cl + j], acc[i][j] + bb[j]);
#pragma unroll
        for (int j = 0; j < 4; ++j)
            unsafeAtomicAdd(&bev[o + chh + j], acc[i][4 + j] + bb[4 + j]);
    }
}

// ---------------- transpose BHWC -> BCHW (writes every output element) ----------------
__global__ __launch_bounds__(256) void transpose_kernel(const float* __restrict__ bev,
                                                        float* __restrict__ out) {
    __shared__ float tile[32][33];
    int tx = threadIdx.x;           // 0..31
    int ty = threadIdx.y;           // 0..7
    int pTile = blockIdx.x * 32;    // position base within HW
    int cTile = blockIdx.y * 32;    // channel base
    int b = blockIdx.z;
    const float* src = bev + (size_t)b * HWD * OUTC;
#pragma unroll
    for (int k = 0; k < 4; ++k) {
        int pos = pTile + ty + k * 8;
        tile[ty + k * 8][tx] = src[(size_t)pos * OUTC + cTile + tx];
    }
    __syncthreads();
    float* dst = out + (size_t)b * OUTC * HWD;
#pragma unroll
    for (int k = 0; k < 4; ++k) {
        int ch = cTile + ty + k * 8;
        dst[(size_t)ch * HWD + pTile + tx] = tile[tx][ty + k * 8];
    }
}

// ---------------- fallback (ws too small): direct scattered atomics into BCHW ----------------
__global__ __launch_bounds__(256) void naive_kernel(
        const float* __restrict__ features, const float* __restrict__ kw,
        const float* __restrict__ bias,
        const int* __restrict__ bidx, const int* __restrict__ d0,
        const int* __restrict__ d1, const int* __restrict__ zi,
        float* __restrict__ out, int n) {
    long long gid = (long long)blockIdx.x * blockDim.x + threadIdx.x;
    int pid = (int)(gid >> 7);
    int c   = (int)(gid & (OUTC - 1));
    if (pid >= n) return;
    int z = zi[pid]; z = z < 0 ? 0 : (z > NZ - 1 ? NZ - 1 : z);
    const float4* fp = (const float4*)(features + (size_t)pid * INC);
    const float* wp = kw + (size_t)z * INC * OUTC + c;
    float a0 = bias[c], a1 = 0.f, a2 = 0.f, a3 = 0.f;
#pragma unroll
    for (int i = 0; i < INC / 4; ++i) {
        float4 f = fp[i];
        a0 += f.x * wp[(size_t)(4 * i + 0) * OUTC];
        a1 += f.y * wp[(size_t)(4 * i + 1) * OUTC];
        a2 += f.z * wp[(size_t)(4 * i + 2) * OUTC];
        a3 += f.w * wp[(size_t)(4 * i + 3) * OUTC];
    }
    float acc = (a0 + a1) + (a2 + a3);
    size_t oidx = ((size_t)bidx[pid] * OUTC + c) * HWD + (size_t)d0[pid] * WWD + d1[pid];
    unsafeAtomicAdd(&out[oidx], acc);
}

extern "C" void kernel_launch(void* const* d_in, const int* in_sizes, int n_in,
                              void* d_out, int out_size, void* d_ws, size_t ws_size,
                              hipStream_t stream) {
    const float* features = (const float*)d_in[0];
    const float* kw       = (const float*)d_in[1];
    const float* bias     = (const float*)d_in[2];
    const int* batch_idx  = (const int*)d_in[3];
    const int* d0_idx     = (const int*)d_in[4];
    const int* d1_idx     = (const int*)d_in[5];
    const int* z_idx      = (const int*)d_in[6];
    float* out = (float*)d_out;
    int n = in_sizes[0] / INC;   // number of points

    size_t bevBytes  = (size_t)NB * HWD * OUTC * sizeof(float);   // 128 MiB
    size_t dumpBytes = 512;                                        // padding dump target
    size_t metaOff   = bevBytes + dumpBytes;
    size_t binsOff   = metaOff + 128;
    size_t binsElems = (size_t)n + (size_t)NZ * PPB;
    size_t need = binsOff + 2 * binsElems * sizeof(int);

    if (ws_size >= need) {
        char* ws = (char*)d_ws;
        float* bev   = (float*)ws;
        int* counts  = (int*)(ws + metaOff);     // 8 ints
        int* cursors = counts + 8;               // 8 ints
        int* pstart  = counts + 16;              // 9 ints
        int* bins    = (int*)(ws + binsOff);
        int* obase   = bins + binsElems;

        hipMemsetAsync(bev, 0, bevBytes, stream);
        hipMemsetAsync(counts, 0, 128, stream);                          // counts+cursors+pstart
        hipMemsetAsync(bins, 0xFF, 2 * binsElems * sizeof(int), stream); // bins + obase = -1

        int gb = (n + 255) / 256;
        hist_kernel<<<gb, 256, 0, stream>>>(z_idx, counts, n);
        prefix_kernel<<<1, 64, 0, stream>>>(counts, pstart, cursors);
        scatter_kernel<<<gb, 256, 0, stream>>>(z_idx, batch_idx, d0_idx, d1_idx,
                                               pstart, cursors, bins, obase, n);

        int nblk = (int)((binsElems + PPB - 1) / PPB) + 1;       // covers padded total
        spmm_kernel<<<nblk, 256, 0, stream>>>(features, kw, bias, pstart, bins, obase, bev);

        dim3 tg(HWD / 32, OUTC / 32, NB), tb(32, 8);
        transpose_kernel<<<tg, tb, 0, stream>>>(bev, out);
    } else {
        hipMemsetAsync(out, 0, (size_t)out_size * sizeof(float), stream);
        long long threads = (long long)n * OUTC;
        int gb = (int)((threads + 255) / 256);
        naive_kernel<<<gb, 256, 0, stream>>>(features, kw, bias, batch_idx, d0_idx,
                                             d1_idx, z_idx, out, n);
    }
}

// Round 5
// 392.381 us; speedup vs baseline: 1.6928x; 1.6928x over previous
//
#include <hip/hip_runtime.h>

#define PPB   128      // points per block (GEMM M-tile)
#define NZ    8
#define INC   64
#define OUTC  128
#define NB    4
#define HH    256
#define WWD   256
#define HWD   (HH * WWD)
#define NSEG  (NB * HH * 2)   // 2048 half-row segments (b, h, w>=128)

__device__ __forceinline__ unsigned bf16_rne(float x) {
    unsigned u = __float_as_uint(x);
    return (u + 0x7FFFu + ((u >> 16) & 1u)) >> 16;
}
__device__ __forceinline__ unsigned pack2(float a, float b) {
    return bf16_rne(a) | (bf16_rne(b) << 16);
}

// ---------------- pass 1: histograms (z bins + half-row segments) ----------------
__global__ void hist_kernel(const int* __restrict__ z_idx, const int* __restrict__ batch_idx,
                            const int* __restrict__ d0_idx, const int* __restrict__ d1_idx,
                            int* __restrict__ counts, int* __restrict__ seghist, int n) {
    __shared__ int lc[NZ];
    int t = threadIdx.x;
    if (t < NZ) lc[t] = 0;
    __syncthreads();
    int i = blockIdx.x * blockDim.x + t;
    if (i < n) {
        int z = z_idx[i]; z = z < 0 ? 0 : (z > NZ - 1 ? NZ - 1 : z);
        atomicAdd(&lc[z], 1);
        int seg = (batch_idx[i] * HH + d0_idx[i]) * 2 + (d1_idx[i] >> 7);
        atomicAdd(&seghist[seg], 1);
    }
    __syncthreads();
    if (t < NZ && lc[t] > 0) atomicAdd(&counts[t], lc[t]);
}

// ---------------- pass 2: prefixes (z padded; segment exclusive scan) ----------------
__global__ void prefix_kernel(const int* __restrict__ counts, int* __restrict__ pstart,
                              const int* __restrict__ seghist, int* __restrict__ segstart) {
    __shared__ int part[256];
    int t = threadIdx.x;
    if (t == 0) {
        int off = 0;
        for (int z = 0; z < NZ; ++z) {
            pstart[z] = off;
            off += ((counts[z] + PPB - 1) / PPB) * PPB;
        }
        pstart[NZ] = off;
    }
    int loc[8]; int s = 0;
#pragma unroll
    for (int j = 0; j < 8; ++j) { loc[j] = seghist[t * 8 + j]; s += loc[j]; }
    part[t] = s;
    __syncthreads();
    for (int d = 1; d < 256; d <<= 1) {
        int v = (t >= d) ? part[t - d] : 0;
        __syncthreads();
        part[t] += v;
        __syncthreads();
    }
    int excl = part[t] - s;
#pragma unroll
    for (int j = 0; j < 8; ++j) { segstart[t * 8 + j] = excl; excl += loc[j]; }
    if (t == 255) segstart[NSEG] = excl;
}

// ---------------- pass 3: scatter ids into z bins + segment lists ----------------
__global__ void scatter_kernel(const int* __restrict__ z_idx, const int* __restrict__ batch_idx,
                               const int* __restrict__ d0_idx, const int* __restrict__ d1_idx,
                               const int* __restrict__ pstart, int* __restrict__ cursors,
                               const int* __restrict__ segstart, int* __restrict__ segcur,
                               int* __restrict__ bins, int* __restrict__ rowlist, int n) {
    __shared__ int lc[NZ];
    __shared__ int lbase[NZ];
    int t = threadIdx.x;
    if (t < NZ) lc[t] = 0;
    __syncthreads();
    int i = blockIdx.x * blockDim.x + t;
    int z = 0, rank = 0;
    bool valid = (i < n);
    if (valid) {
        z = z_idx[i]; z = z < 0 ? 0 : (z > NZ - 1 ? NZ - 1 : z);
        rank = atomicAdd(&lc[z], 1);
    }
    __syncthreads();
    if (t < NZ) lbase[t] = (lc[t] > 0) ? atomicAdd(&cursors[t], lc[t]) : 0;
    __syncthreads();
    if (valid) {
        int slot = pstart[z] + lbase[z] + rank;
        bins[slot] = i;
        int w = d1_idx[i];
        int seg = (batch_idx[i] * HH + d0_idx[i]) * 2 + (w >> 7);
        int r2 = atomicAdd(&segcur[seg], 1);
        rowlist[segstart[seg] + r2] = (slot << 7) | (w & 127);   // slot<2^19, fits
    }
}

// ---------------- pass 4: LDS-tiled fp32 GEMM per z-bin -> bf16 bev_feat (no atomics) ----------------
__global__ __launch_bounds__(256) void gemm_kernel(
        const float* __restrict__ features, const float* __restrict__ kw,
        const float* __restrict__ bias,
        const int* __restrict__ pstart, const int* __restrict__ bins,
        unsigned* __restrict__ bevf) {
    __shared__ __align__(16) float A[INC][PPB];     // 32 KiB, [k][p]
    __shared__ __align__(16) float Wl[INC][OUTC];   // 32 KiB, [k][c]

    int start = blockIdx.x * PPB;
    int total = pstart[NZ];
    if (start >= total) return;
    int z = 0;
#pragma unroll
    for (int zz = 1; zz < NZ; ++zz)
        if (start >= pstart[zz]) z = zz;

    int tid = threadIdx.x;
    {   // stage W[z]: straight 32KB copy
        const float4* src = (const float4*)(kw + (size_t)z * INC * OUTC);
        float4* dst = (float4*)&Wl[0][0];
#pragma unroll
        for (int i = 0; i < 8; ++i) dst[tid + 256 * i] = src[tid + 256 * i];
    }
    {   // stage A: gather 128 feature rows, write transposed [k][p]
        int r = tid >> 1;
        int half = tid & 1;
        int raw = bins[start + r];
        int nid = raw < 0 ? 0 : raw;       // padding -> row 0 (slot never referenced)
        const float4* fp = (const float4*)(features + (size_t)nid * INC) + half * 8;
#pragma unroll
        for (int q = 0; q < 8; ++q) {
            float4 f = fp[q];
            int k = half * 32 + q * 4;
            A[k + 0][r] = f.x; A[k + 1][r] = f.y; A[k + 2][r] = f.z; A[k + 3][r] = f.w;
        }
    }
    __syncthreads();

    int tc = tid & 15;
    int tp = tid >> 4;
    int p0 = tp * 8;
    int cl = tc * 4;
    int chh = 64 + cl;

    float acc[8][8];
#pragma unroll
    for (int i = 0; i < 8; ++i)
#pragma unroll
        for (int j = 0; j < 8; ++j) acc[i][j] = 0.f;

#pragma unroll 4
    for (int k = 0; k < INC; ++k) {
        float4 b0 = *(const float4*)&Wl[k][cl];
        float4 b1 = *(const float4*)&Wl[k][chh];
        float4 a0 = *(const float4*)&A[k][p0];
        float4 a1 = *(const float4*)&A[k][p0 + 4];
        float ar[8] = {a0.x, a0.y, a0.z, a0.w, a1.x, a1.y, a1.z, a1.w};
        float br[8] = {b0.x, b0.y, b0.z, b0.w, b1.x, b1.y, b1.z, b1.w};
#pragma unroll
        for (int i = 0; i < 8; ++i)
#pragma unroll
            for (int j = 0; j < 8; ++j)
                acc[i][j] += ar[i] * br[j];
    }

    float4 blo = *(const float4*)&bias[cl];
    float4 bhi = *(const float4*)&bias[chh];
    float bb[8] = {blo.x, blo.y, blo.z, blo.w, bhi.x, bhi.y, bhi.z, bhi.w};
#pragma unroll
    for (int i = 0; i < 8; ++i) {
        size_t slot = (size_t)(start + p0 + i);
        uint2* dst = (uint2*)bevf + slot * 32;
        uint2 lo, hi;
        lo.x = pack2(acc[i][0] + bb[0], acc[i][1] + bb[1]);
        lo.y = pack2(acc[i][2] + bb[2], acc[i][3] + bb[3]);
        hi.x = pack2(acc[i][4] + bb[4], acc[i][5] + bb[5]);
        hi.y = pack2(acc[i][6] + bb[6], acc[i][7] + bb[7]);
        dst[tc]      = lo;    // channels cl..cl+3   (128B contiguous per tp-group)
        dst[16 + tc] = hi;    // channels 64+cl..+3
    }
}

// ---------------- pass 5: per-segment LDS reduction -> direct BCHW writeout ----------------
// One block = one (b, h, w-half) segment: 128 cells x 128 channels in 64KB LDS.
// Additive swizzle cs=(c+w)&127 keeps both LDS-atomic and transpose-read at <=2-way.
__global__ __launch_bounds__(256) void reduce_kernel(
        const unsigned* __restrict__ bevf, const int* __restrict__ segstart,
        const int* __restrict__ rowlist, float* __restrict__ out) {
    __shared__ float lds[128 * 128];   // 64 KiB
    int t = threadIdx.x;
    int seg = blockIdx.x;

    float4* z4 = (float4*)lds;
#pragma unroll
    for (int i = 0; i < 16; ++i) z4[t + 256 * i] = make_float4(0.f, 0.f, 0.f, 0.f);
    __syncthreads();

    int s0 = segstart[seg], s1 = segstart[seg + 1];
    int wv = t >> 6, l = t & 63;
    int e = s0 + wv;
    int entry = (e < s1) ? rowlist[e] : -1;
    while (entry >= 0) {
        int en = e + 4;
        int nentry = (en < s1) ? rowlist[en] : -1;   // prefetch next
        int slot = entry >> 7, w = entry & 127;
        unsigned v = bevf[(size_t)slot * 64 + l];    // 256B coalesced per wave
        float f0 = __uint_as_float(v << 16);
        float f1 = __uint_as_float(v & 0xFFFF0000u);
        int c0 = 2 * l;
        atomicAdd(&lds[w * 128 + ((c0 + w) & 127)], f0);
        atomicAdd(&lds[w * 128 + ((c0 + 1 + w) & 127)], f1);
        e = en; entry = nentry;
    }
    __syncthreads();

    int b = seg >> 9, h = (seg >> 1) & 255, wh = seg & 1;
    int w = t & 127;
    int chalf = t >> 7;
    float* obase = out + (size_t)b * OUTC * HWD + (size_t)h * WWD + wh * 128;
#pragma unroll
    for (int ci = 0; ci < 64; ++ci) {
        int c = ci * 2 + chalf;
        obase[(size_t)c * HWD + w] = lds[w * 128 + ((c + w) & 127)];
    }
}

// ---------------- fallback (ws too small): direct scattered atomics into BCHW ----------------
__global__ __launch_bounds__(256) void naive_kernel(
        const float* __restrict__ features, const float* __restrict__ kw,
        const float* __restrict__ bias,
        const int* __restrict__ bidx, const int* __restrict__ d0,
        const int* __restrict__ d1, const int* __restrict__ zi,
        float* __restrict__ out, int n) {
    long long gid = (long long)blockIdx.x * blockDim.x + threadIdx.x;
    int pid = (int)(gid >> 7);
    int c   = (int)(gid & (OUTC - 1));
    if (pid >= n) return;
    int z = zi[pid]; z = z < 0 ? 0 : (z > NZ - 1 ? NZ - 1 : z);
    const float4* fp = (const float4*)(features + (size_t)pid * INC);
    const float* wp = kw + (size_t)z * INC * OUTC + c;
    float a0 = bias[c], a1 = 0.f, a2 = 0.f, a3 = 0.f;
#pragma unroll
    for (int i = 0; i < INC / 4; ++i) {
        float4 f = fp[i];
        a0 += f.x * wp[(size_t)(4 * i + 0) * OUTC];
        a1 += f.y * wp[(size_t)(4 * i + 1) * OUTC];
        a2 += f.z * wp[(size_t)(4 * i + 2) * OUTC];
        a3 += f.w * wp[(size_t)(4 * i + 3) * OUTC];
    }
    float acc = (a0 + a1) + (a2 + a3);
    size_t oidx = ((size_t)bidx[pid] * OUTC + c) * HWD + (size_t)d0[pid] * WWD + d1[pid];
    unsafeAtomicAdd(&out[oidx], acc);
}

extern "C" void kernel_launch(void* const* d_in, const int* in_sizes, int n_in,
                              void* d_out, int out_size, void* d_ws, size_t ws_size,
                              hipStream_t stream) {
    const float* features = (const float*)d_in[0];
    const float* kw       = (const float*)d_in[1];
    const float* bias     = (const float*)d_in[2];
    const int* batch_idx  = (const int*)d_in[3];
    const int* d0_idx     = (const int*)d_in[4];
    const int* d1_idx     = (const int*)d_in[5];
    const int* z_idx      = (const int*)d_in[6];
    float* out = (float*)d_out;
    int n = in_sizes[0] / INC;   // number of points

    size_t binsElems = (size_t)n + (size_t)NZ * PPB;
    // ws layout: bevf (bf16 rows) | meta | bins | rowlist
    size_t bevfBytes = binsElems * OUTC * 2;                 // ~77 MB
    size_t metaOff   = (bevfBytes + 255) & ~(size_t)255;
    // meta ints: [0..7]=counts [8..15]=cursors [16..24]=pstart
    //            [32..2079]=seghist [2080..4127]=segcur [4128..6176]=segstart
    size_t metaInts  = 6192;
    size_t binsOff   = (metaOff + metaInts * 4 + 255) & ~(size_t)255;
    size_t rowOff    = binsOff + binsElems * 4;
    size_t need      = rowOff + (size_t)n * 4;

    if (ws_size >= need) {
        char* ws = (char*)d_ws;
        unsigned* bevf = (unsigned*)ws;
        int* meta     = (int*)(ws + metaOff);
        int* counts   = meta;
        int* cursors  = meta + 8;
        int* pstart   = meta + 16;
        int* seghist  = meta + 32;
        int* segcur   = meta + 32 + NSEG;
        int* segstart = meta + 32 + 2 * NSEG;
        int* bins     = (int*)(ws + binsOff);
        int* rowlist  = (int*)(ws + rowOff);

        hipMemsetAsync(meta, 0, metaInts * 4, stream);                 // counts/cursors/hists
        hipMemsetAsync(bins, 0xFF, binsElems * 4, stream);             // -1 padding

        int gb = (n + 255) / 256;
        hist_kernel<<<gb, 256, 0, stream>>>(z_idx, batch_idx, d0_idx, d1_idx,
                                            counts, seghist, n);
        prefix_kernel<<<1, 256, 0, stream>>>(counts, pstart, seghist, segstart);
        scatter_kernel<<<gb, 256, 0, stream>>>(z_idx, batch_idx, d0_idx, d1_idx,
                                               pstart, cursors, segstart, segcur,
                                               bins, rowlist, n);

        int nblk = (int)((binsElems + PPB - 1) / PPB) + 1;
        gemm_kernel<<<nblk, 256, 0, stream>>>(features, kw, bias, pstart, bins, bevf);

        reduce_kernel<<<NSEG, 256, 0, stream>>>(bevf, segstart, rowlist, out);
    } else {
        hipMemsetAsync(out, 0, (size_t)out_size * sizeof(float), stream);
        long long threads = (long long)n * OUTC;
        int gb = (int)((threads + 255) / 256);
        naive_kernel<<<gb, 256, 0, stream>>>(features, kw, bias, batch_idx, d0_idx,
                                             d1_idx, z_idx, out, n);
    }
}

// Round 6
// 371.499 us; speedup vs baseline: 1.7880x; 1.0562x over previous
//
#include <hip/hip_runtime.h>

#define PPB   128      // points per block (GEMM M-tile)
#define NZ    8
#define INC   64
#define OUTC  128
#define NB    4
#define HH    256
#define WWD   256
#define HWD   (HH * WWD)
#define NSEG  (NB * HH * 4)   // 4096 quarter-row segments (b, h, w>>6)

__device__ __forceinline__ unsigned bf16_rne(float x) {
    unsigned u = __float_as_uint(x);
    return (u + 0x7FFFu + ((u >> 16) & 1u)) >> 16;
}
__device__ __forceinline__ unsigned pack2(float lo, float hi) {
    return bf16_rne(lo) | (bf16_rne(hi) << 16);
}

// ---------------- pass 1: histograms (z bins + quarter-row segments) ----------------
__global__ void hist_kernel(const int* __restrict__ z_idx, const int* __restrict__ batch_idx,
                            const int* __restrict__ d0_idx, const int* __restrict__ d1_idx,
                            int* __restrict__ counts, int* __restrict__ seghist, int n) {
    __shared__ int lc[NZ];
    int t = threadIdx.x;
    if (t < NZ) lc[t] = 0;
    __syncthreads();
    int i = blockIdx.x * blockDim.x + t;
    if (i < n) {
        int z = z_idx[i]; z = z < 0 ? 0 : (z > NZ - 1 ? NZ - 1 : z);
        atomicAdd(&lc[z], 1);
        int seg = ((batch_idx[i] * HH + d0_idx[i]) << 2) | (d1_idx[i] >> 6);
        atomicAdd(&seghist[seg], 1);
    }
    __syncthreads();
    if (t < NZ && lc[t] > 0) atomicAdd(&counts[t], lc[t]);
}

// ---------------- pass 2: prefixes (z padded; segment exclusive scan over 4096) ----------------
__global__ void prefix_kernel(const int* __restrict__ counts, int* __restrict__ pstart,
                              const int* __restrict__ seghist, int* __restrict__ segstart) {
    __shared__ int part[256];
    int t = threadIdx.x;
    if (t == 0) {
        int off = 0;
        for (int z = 0; z < NZ; ++z) {
            pstart[z] = off;
            off += ((counts[z] + PPB - 1) / PPB) * PPB;
        }
        pstart[NZ] = off;
    }
    int loc[16]; int s = 0;
#pragma unroll
    for (int j = 0; j < 16; ++j) { loc[j] = seghist[t * 16 + j]; s += loc[j]; }
    part[t] = s;
    __syncthreads();
    for (int d = 1; d < 256; d <<= 1) {
        int v = (t >= d) ? part[t - d] : 0;
        __syncthreads();
        part[t] += v;
        __syncthreads();
    }
    int excl = part[t] - s;
#pragma unroll
    for (int j = 0; j < 16; ++j) { segstart[t * 16 + j] = excl; excl += loc[j]; }
    if (t == 255) segstart[NSEG] = excl;
}

// ---------------- pass 3: scatter ids into z bins + segment-ordered positions ----------------
__global__ void scatter_kernel(const int* __restrict__ z_idx, const int* __restrict__ batch_idx,
                               const int* __restrict__ d0_idx, const int* __restrict__ d1_idx,
                               const int* __restrict__ pstart, int* __restrict__ cursors,
                               const int* __restrict__ segstart, int* __restrict__ segcur,
                               int* __restrict__ bins, int* __restrict__ segpos,
                               unsigned short* __restrict__ wlist, int n) {
    __shared__ int lc[NZ];
    __shared__ int lbase[NZ];
    int t = threadIdx.x;
    if (t < NZ) lc[t] = 0;
    __syncthreads();
    int i = blockIdx.x * blockDim.x + t;
    int z = 0, rank = 0;
    bool valid = (i < n);
    if (valid) {
        z = z_idx[i]; z = z < 0 ? 0 : (z > NZ - 1 ? NZ - 1 : z);
        rank = atomicAdd(&lc[z], 1);
    }
    __syncthreads();
    if (t < NZ) lbase[t] = (lc[t] > 0) ? atomicAdd(&cursors[t], lc[t]) : 0;
    __syncthreads();
    if (valid) {
        int slot = pstart[z] + lbase[z] + rank;
        bins[slot] = i;
        int w = d1_idx[i];
        int seg = ((batch_idx[i] * HH + d0_idx[i]) << 2) | (w >> 6);
        int r2 = atomicAdd(&segcur[seg], 1);
        int sp = segstart[seg] + r2;
        segpos[slot] = 1 + sp;               // row 0 of bevf = dump for padding
        wlist[sp] = (unsigned short)(w & 63);
    }
}

// ---------------- pass 4: LDS-tiled fp32 GEMM per z-bin -> bf16 rows at segment-ordered pos ----------------
// dword d of a row packs channels (d, d+64) as (lo16, hi16).
__global__ __launch_bounds__(256) void gemm_kernel(
        const float* __restrict__ features, const float* __restrict__ kw,
        const float* __restrict__ bias,
        const int* __restrict__ pstart, const int* __restrict__ bins,
        const int* __restrict__ segpos, unsigned* __restrict__ bevf) {
    __shared__ __align__(16) float A[INC][PPB];     // 32 KiB, [k][p]
    __shared__ __align__(16) float Wl[INC][OUTC];   // 32 KiB, [k][c]

    int start = blockIdx.x * PPB;
    int total = pstart[NZ];
    if (start >= total) return;
    int z = 0;
#pragma unroll
    for (int zz = 1; zz < NZ; ++zz)
        if (start >= pstart[zz]) z = zz;

    int tid = threadIdx.x;
    int tc = tid & 15;
    int tp = tid >> 4;
    int p0 = tp * 8;

    // prefetch output positions (independent loads, hidden under staging+compute)
    int posArr[8];
#pragma unroll
    for (int i = 0; i < 8; ++i) posArr[i] = segpos[start + p0 + i];

    {   // stage W[z]: straight 32KB copy
        const float4* src = (const float4*)(kw + (size_t)z * INC * OUTC);
        float4* dst = (float4*)&Wl[0][0];
#pragma unroll
        for (int i = 0; i < 8; ++i) dst[tid + 256 * i] = src[tid + 256 * i];
    }
    {   // stage A: gather 128 feature rows, write transposed [k][p]
        int r = tid >> 1;
        int half = tid & 1;
        int raw = bins[start + r];
        int nid = raw < 0 ? 0 : raw;       // padding -> row 0 (goes to dump)
        const float4* fp = (const float4*)(features + (size_t)nid * INC) + half * 8;
#pragma unroll
        for (int q = 0; q < 8; ++q) {
            float4 f = fp[q];
            int k = half * 32 + q * 4;
            A[k + 0][r] = f.x; A[k + 1][r] = f.y; A[k + 2][r] = f.z; A[k + 3][r] = f.w;
        }
    }
    __syncthreads();

    int cl = tc * 4;
    int chh = 64 + cl;

    float acc[8][8];
#pragma unroll
    for (int i = 0; i < 8; ++i)
#pragma unroll
        for (int j = 0; j < 8; ++j) acc[i][j] = 0.f;

#pragma unroll 4
    for (int k = 0; k < INC; ++k) {
        float4 b0 = *(const float4*)&Wl[k][cl];
        float4 b1 = *(const float4*)&Wl[k][chh];
        float4 a0 = *(const float4*)&A[k][p0];
        float4 a1 = *(const float4*)&A[k][p0 + 4];
        float ar[8] = {a0.x, a0.y, a0.z, a0.w, a1.x, a1.y, a1.z, a1.w};
        float br[8] = {b0.x, b0.y, b0.z, b0.w, b1.x, b1.y, b1.z, b1.w};
#pragma unroll
        for (int i = 0; i < 8; ++i)
#pragma unroll
            for (int j = 0; j < 8; ++j)
                acc[i][j] += ar[i] * br[j];
    }

    float4 blo = *(const float4*)&bias[cl];
    float4 bhi = *(const float4*)&bias[chh];
    float bb[8] = {blo.x, blo.y, blo.z, blo.w, bhi.x, bhi.y, bhi.z, bhi.w};
#pragma unroll
    for (int i = 0; i < 8; ++i) {
        uint4* row = (uint4*)bevf + (size_t)posArr[i] * 16;
        uint4 pk;
        pk.x = pack2(acc[i][0] + bb[0], acc[i][4] + bb[4]);
        pk.y = pack2(acc[i][1] + bb[1], acc[i][5] + bb[5]);
        pk.z = pack2(acc[i][2] + bb[2], acc[i][6] + bb[6]);
        pk.w = pack2(acc[i][3] + bb[3], acc[i][7] + bb[7]);
        row[tc] = pk;     // 16 lanes x 16B = 256B full-cacheline store per point
    }
}

// ---------------- pass 5: streaming per-segment reduction -> direct BCHW writeout ----------------
// Block = one quarter-row segment (64 cells x 128 ch, 32KB LDS). All addresses are
// known from segstart alone -> pure streaming reads, known trip counts, full MLP.
__global__ __launch_bounds__(256) void reduce_kernel(
        const unsigned* __restrict__ bevf, const int* __restrict__ segstart,
        const unsigned short* __restrict__ wlist, float* __restrict__ out) {
    __shared__ float lds[64 * 128];   // 32 KiB
    int t = threadIdx.x;
    int seg = blockIdx.x;

    float4* z4 = (float4*)lds;
#pragma unroll
    for (int i = 0; i < 8; ++i) z4[t + 256 * i] = make_float4(0.f, 0.f, 0.f, 0.f);
    __syncthreads();

    int s0 = segstart[seg], s1 = segstart[seg + 1];
    int cnt = s1 - s0;
    if (cnt > 0) {
        int wv = t >> 6, l = t & 63;
        int chunk = (cnt + 3) >> 2;
        int myBeg = s0 + wv * chunk;
        int myEnd = myBeg + chunk; if (myEnd > s1) myEnd = s1;
        for (int e = myBeg; e < myEnd; e += 4) {
            unsigned v[4]; int wc[4]; bool val[4];
#pragma unroll
            for (int u = 0; u < 4; ++u) {
                int idx = e + u;
                val[u] = idx < myEnd;
                if (!val[u]) idx = myEnd - 1;
                wc[u] = wlist[idx];                       // wave-uniform broadcast
                v[u]  = bevf[(size_t)(idx + 1) * 64 + l]; // 256B coalesced stream
            }
#pragma unroll
            for (int u = 0; u < 4; ++u) if (val[u]) {
                float f0 = __uint_as_float(v[u] << 16);         // channel l
                float f1 = __uint_as_float(v[u] & 0xFFFF0000u); // channel l+64
                int w = wc[u];
                atomicAdd(&lds[w * 128 + ((l      + w) & 127)], f0);
                atomicAdd(&lds[w * 128 + ((l + 64 + w) & 127)], f1);
            }
        }
    }
    __syncthreads();

    int b = seg >> 10, h = (seg >> 2) & 255, wq = seg & 3;
    int w = t & 63, q = t >> 6;
    float* obase = out + (size_t)b * OUTC * HWD + (size_t)h * WWD + wq * 64;
#pragma unroll
    for (int ci = 0; ci < 32; ++ci) {
        int c = q * 32 + ci;
        obase[(size_t)c * HWD + w] = lds[w * 128 + ((c + w) & 127)];
    }
}

// ---------------- fallback (ws too small): direct scattered atomics into BCHW ----------------
__global__ __launch_bounds__(256) void naive_kernel(
        const float* __restrict__ features, const float* __restrict__ kw,
        const float* __restrict__ bias,
        const int* __restrict__ bidx, const int* __restrict__ d0,
        const int* __restrict__ d1, const int* __restrict__ zi,
        float* __restrict__ out, int n) {
    long long gid = (long long)blockIdx.x * blockDim.x + threadIdx.x;
    int pid = (int)(gid >> 7);
    int c   = (int)(gid & (OUTC - 1));
    if (pid >= n) return;
    int z = zi[pid]; z = z < 0 ? 0 : (z > NZ - 1 ? NZ - 1 : z);
    const float4* fp = (const float4*)(features + (size_t)pid * INC);
    const float* wp = kw + (size_t)z * INC * OUTC + c;
    float a0 = bias[c], a1 = 0.f, a2 = 0.f, a3 = 0.f;
#pragma unroll
    for (int i = 0; i < INC / 4; ++i) {
        float4 f = fp[i];
        a0 += f.x * wp[(size_t)(4 * i + 0) * OUTC];
        a1 += f.y * wp[(size_t)(4 * i + 1) * OUTC];
        a2 += f.z * wp[(size_t)(4 * i + 2) * OUTC];
        a3 += f.w * wp[(size_t)(4 * i + 3) * OUTC];
    }
    float acc = (a0 + a1) + (a2 + a3);
    size_t oidx = ((size_t)bidx[pid] * OUTC + c) * HWD + (size_t)d0[pid] * WWD + d1[pid];
    unsafeAtomicAdd(&out[oidx], acc);
}

extern "C" void kernel_launch(void* const* d_in, const int* in_sizes, int n_in,
                              void* d_out, int out_size, void* d_ws, size_t ws_size,
                              hipStream_t stream) {
    const float* features = (const float*)d_in[0];
    const float* kw       = (const float*)d_in[1];
    const float* bias     = (const float*)d_in[2];
    const int* batch_idx  = (const int*)d_in[3];
    const int* d0_idx     = (const int*)d_in[4];
    const int* d1_idx     = (const int*)d_in[5];
    const int* z_idx      = (const int*)d_in[6];
    float* out = (float*)d_out;
    int n = in_sizes[0] / INC;   // number of points

    size_t binsElems = (size_t)n + (size_t)NZ * PPB;
    // ws layout: bevf rows (1 dump + binsElems) | meta | bins | segpos | wlist
    size_t bevfBytes = (binsElems + 1) * OUTC * 2;           // ~77.5 MB
    size_t metaOff   = (bevfBytes + 255) & ~(size_t)255;
    // meta ints: [0..7]=counts [8..15]=cursors [16..24]=pstart
    //            [32..]=seghist(4096) segcur(4096) segstart(4097)
    size_t metaInts  = 32 + 3 * NSEG + 16;
    size_t binsOff   = (metaOff + metaInts * 4 + 255) & ~(size_t)255;
    size_t posOff    = binsOff + binsElems * 4;
    size_t wlistOff  = posOff + binsElems * 4;
    size_t need      = wlistOff + (size_t)n * 2 + 16;

    if (ws_size >= need) {
        char* ws = (char*)d_ws;
        unsigned* bevf = (unsigned*)ws;
        int* meta     = (int*)(ws + metaOff);
        int* counts   = meta;
        int* cursors  = meta + 8;
        int* pstart   = meta + 16;
        int* seghist  = meta + 32;
        int* segcur   = meta + 32 + NSEG;
        int* segstart = meta + 32 + 2 * NSEG;
        int* bins     = (int*)(ws + binsOff);
        int* segpos   = (int*)(ws + posOff);
        unsigned short* wlist = (unsigned short*)(ws + wlistOff);

        hipMemsetAsync(meta, 0, metaInts * 4, stream);
        hipMemsetAsync(bins, 0xFF, binsElems * 4, stream);   // -1 padding
        hipMemsetAsync(segpos, 0, binsElems * 4, stream);    // padding -> dump row 0

        int gb = (n + 255) / 256;
        hist_kernel<<<gb, 256, 0, stream>>>(z_idx, batch_idx, d0_idx, d1_idx,
                                            counts, seghist, n);
        prefix_kernel<<<1, 256, 0, stream>>>(counts, pstart, seghist, segstart);
        scatter_kernel<<<gb, 256, 0, stream>>>(z_idx, batch_idx, d0_idx, d1_idx,
                                               pstart, cursors, segstart, segcur,
                                               bins, segpos, wlist, n);

        int nblk = (int)((binsElems + PPB - 1) / PPB) + 1;
        gemm_kernel<<<nblk, 256, 0, stream>>>(features, kw, bias, pstart, bins,
                                              segpos, bevf);

        reduce_kernel<<<NSEG, 256, 0, stream>>>(bevf, segstart, wlist, out);
    } else {
        hipMemsetAsync(out, 0, (size_t)out_size * sizeof(float), stream);
        long long threads = (long long)n * OUTC;
        int gb = (int)((threads + 255) / 256);
        naive_kernel<<<gb, 256, 0, stream>>>(features, kw, bias, batch_idx, d0_idx,
                                             d1_idx, z_idx, out, n);
    }
}